// Round 1
// baseline (776.036 us; speedup 1.0000x reference)
//
#include <hip/hip_runtime.h>

#define N_NODES 50000
#define N_EDGES 800000
#define D_INN 100
#define HID 128
#define N_GRAPHS 64
#define NBLK ((N_NODES + 255) / 256)   // 196

// ---------------- init: deg=1 (self loop), cnt=0 ----------------
__global__ void k_init(int* __restrict__ deg, int* __restrict__ cnt) {
    int i = blockIdx.x * 256 + threadIdx.x;
    if (i < N_NODES) { deg[i] = 1; cnt[i] = 0; }
}

// ---------------- degree accumulation over edges ----------------
__global__ void k_deg(const int* __restrict__ dst, int* __restrict__ deg) {
    int e = blockIdx.x * 256 + threadIdx.x;
    if (e < N_EDGES) atomicAdd(&deg[dst[e]], 1);
}

__global__ void k_dinv(const int* __restrict__ deg, float* __restrict__ dinv) {
    int i = blockIdx.x * 256 + threadIdx.x;
    if (i < N_NODES) dinv[i] = rsqrtf((float)deg[i]);
}

// ---------------- two-level scan: offsets = exclusive prefix of deg ----------------
__global__ __launch_bounds__(256) void k_scan1(const int* __restrict__ deg,
                                               int* __restrict__ incl,
                                               int* __restrict__ bsums) {
    __shared__ int sm[256];
    int i = blockIdx.x * 256 + threadIdx.x;
    int v = (i < N_NODES) ? deg[i] : 0;
    sm[threadIdx.x] = v;
    __syncthreads();
    for (int off = 1; off < 256; off <<= 1) {
        int t = (threadIdx.x >= off) ? sm[threadIdx.x - off] : 0;
        __syncthreads();
        sm[threadIdx.x] += t;
        __syncthreads();
    }
    if (i < N_NODES) incl[i] = sm[threadIdx.x];
    if (threadIdx.x == 255) bsums[blockIdx.x] = sm[255];
}

__global__ __launch_bounds__(256) void k_scan2(const int* __restrict__ bsums,
                                               int* __restrict__ boff) {
    __shared__ int sm[256];
    int v = (threadIdx.x < NBLK) ? bsums[threadIdx.x] : 0;
    sm[threadIdx.x] = v;
    __syncthreads();
    for (int off = 1; off < 256; off <<= 1) {
        int t = (threadIdx.x >= off) ? sm[threadIdx.x - off] : 0;
        __syncthreads();
        sm[threadIdx.x] += t;
        __syncthreads();
    }
    boff[threadIdx.x] = sm[threadIdx.x] - v;   // exclusive
}

__global__ void k_scan3(const int* __restrict__ incl, const int* __restrict__ boff,
                        int* __restrict__ offsets) {
    int i = blockIdx.x * 256 + threadIdx.x;
    if (i < N_NODES) offsets[i + 1] = incl[i] + boff[blockIdx.x];
    if (i == 0) offsets[0] = 0;
}

// ---------------- CSR fill (edges + self loops) ----------------
__global__ void k_fill(const int* __restrict__ src, const int* __restrict__ dst,
                       const float* __restrict__ dinv, const int* __restrict__ offsets,
                       int* __restrict__ cnt, int* __restrict__ csr_src,
                       float* __restrict__ csr_norm) {
    int e = blockIdx.x * 256 + threadIdx.x;
    if (e < N_EDGES) {
        int s = src[e], d = dst[e];
        int pos = offsets[d] + atomicAdd(&cnt[d], 1);
        csr_src[pos]  = s;
        csr_norm[pos] = dinv[s] * dinv[d];
    } else if (e < N_EDGES + N_NODES) {
        int i = e - N_EDGES;
        int pos = offsets[i] + atomicAdd(&cnt[i], 1);
        csr_src[pos]  = i;
        csr_norm[pos] = dinv[i] * dinv[i];
    }
}

// ---------------- GEMM: out[N,128] = in[N,K] @ W[K,128] (+bias) ----------------
// 256 threads: 32 col-quads x 8 row-groups; each thread 4 rows x 4 cols.
// W fully in LDS; 32-row input panels staged per chunk; grid-stride over chunks.
template <int K, bool BIAS>
__global__ __launch_bounds__(256) void k_gemm(const float* __restrict__ in,
                                              const float* __restrict__ W,
                                              const float* __restrict__ bias,
                                              float* __restrict__ out) {
    __shared__ float lw[K * HID];
    __shared__ float lx[32 * K];
    for (int i = threadIdx.x; i < K * HID / 4; i += 256)
        ((float4*)lw)[i] = ((const float4*)W)[i];
    const int cq = threadIdx.x & 31;   // cols 4*cq .. 4*cq+3
    const int rg = threadIdx.x >> 5;   // rows rg, rg+8, rg+16, rg+24
    float4 zero; zero.x = zero.y = zero.z = zero.w = 0.f;
    float4 bv = zero;
    if (BIAS) bv = ((const float4*)bias)[cq];
    const float4* lw4 = (const float4*)lw;
    const int nch = (N_NODES + 31) / 32;
    for (int c = blockIdx.x; c < nch; c += gridDim.x) {
        int r0 = c * 32;
        __syncthreads();
        for (int i = threadIdx.x; i < 32 * K / 4; i += 256) {
            int fi = i * 4;
            int rr = fi / K, kk = fi % K;
            int gr = r0 + rr;
            ((float4*)lx)[i] = (gr < N_NODES) ? *(const float4*)(in + gr * K + kk) : zero;
        }
        __syncthreads();
        float4 a0 = bv, a1 = bv, a2 = bv, a3 = bv;
#pragma unroll 8
        for (int k = 0; k < K; ++k) {
            float4 w = lw4[k * 32 + cq];
            float x0 = lx[(rg +  0) * K + k];
            float x1 = lx[(rg +  8) * K + k];
            float x2 = lx[(rg + 16) * K + k];
            float x3 = lx[(rg + 24) * K + k];
            a0.x = fmaf(x0, w.x, a0.x); a0.y = fmaf(x0, w.y, a0.y);
            a0.z = fmaf(x0, w.z, a0.z); a0.w = fmaf(x0, w.w, a0.w);
            a1.x = fmaf(x1, w.x, a1.x); a1.y = fmaf(x1, w.y, a1.y);
            a1.z = fmaf(x1, w.z, a1.z); a1.w = fmaf(x1, w.w, a1.w);
            a2.x = fmaf(x2, w.x, a2.x); a2.y = fmaf(x2, w.y, a2.y);
            a2.z = fmaf(x2, w.z, a2.z); a2.w = fmaf(x2, w.w, a2.w);
            a3.x = fmaf(x3, w.x, a3.x); a3.y = fmaf(x3, w.y, a3.y);
            a3.z = fmaf(x3, w.z, a3.z); a3.w = fmaf(x3, w.w, a3.w);
        }
        int gr = r0 + rg;
        if (gr      < N_NODES) *(float4*)(out + (gr     ) * HID + cq * 4) = a0;
        if (gr +  8 < N_NODES) *(float4*)(out + (gr +  8) * HID + cq * 4) = a1;
        if (gr + 16 < N_NODES) *(float4*)(out + (gr + 16) * HID + cq * 4) = a2;
        if (gr + 24 < N_NODES) *(float4*)(out + (gr + 24) * HID + cq * 4) = a3;
    }
}

// ---------------- aggregation: A[n] = relu(sum_{j in CSR(n)} norm_j * B[src_j] + b) ----
// one wave per node, float2 per lane (128 cols / 64 lanes)
__global__ __launch_bounds__(256) void k_agg(const float* __restrict__ B,
                                             const int* __restrict__ offsets,
                                             const int* __restrict__ csr_src,
                                             const float* __restrict__ csr_norm,
                                             const float* __restrict__ bias,
                                             float* __restrict__ A) {
    int node = (blockIdx.x * 256 + threadIdx.x) >> 6;
    int lane = threadIdx.x & 63;
    if (node >= N_NODES) return;
    int beg = offsets[node], end = offsets[node + 1];
    float accx = 0.f, accy = 0.f;
    const float2* B2 = (const float2*)B;
    for (int j = beg; j < end; ++j) {
        int s = csr_src[j];
        float nv = csr_norm[j];
        float2 v = B2[s * 64 + lane];
        accx = fmaf(nv, v.x, accx);
        accy = fmaf(nv, v.y, accy);
    }
    float2 b = ((const float2*)bias)[lane];
    float2 r;
    r.x = fmaxf(accx + b.x, 0.f);
    r.y = fmaxf(accy + b.y, 0.f);
    ((float2*)A)[node * 64 + lane] = r;
}

// ---------------- mean pool per graph (batch sorted -> binary search bounds) ------
__global__ __launch_bounds__(128) void k_pool(const float* __restrict__ A,
                                              const int* __restrict__ batch,
                                              float* __restrict__ pooled) {
    int g = blockIdx.x;
    int lo = 0, hi = N_NODES;
    while (lo < hi) { int mid = (lo + hi) >> 1; if (batch[mid] < g) lo = mid + 1; else hi = mid; }
    int start = lo;
    hi = N_NODES;
    while (lo < hi) { int mid = (lo + hi) >> 1; if (batch[mid] < g + 1) lo = mid + 1; else hi = mid; }
    int end = lo;
    float acc = 0.f;
    for (int n = start; n < end; ++n) acc += A[n * HID + threadIdx.x];
    float cnt = (float)((end - start) > 0 ? (end - start) : 1);
    pooled[g * HID + threadIdx.x] = acc / cnt;
}

// ---------------- head: out[g] = dot(pooled[g], W_reg) + b_reg ----------------
__global__ __launch_bounds__(128) void k_head(const float* __restrict__ pooled,
                                              const float* __restrict__ W_reg,
                                              const float* __restrict__ b_reg,
                                              float* __restrict__ out) {
    int g = blockIdx.x;
    float v = pooled[g * HID + threadIdx.x] * W_reg[threadIdx.x];
    for (int off = 32; off > 0; off >>= 1) v += __shfl_down(v, off);
    __shared__ float sm[2];
    if ((threadIdx.x & 63) == 0) sm[threadIdx.x >> 6] = v;
    __syncthreads();
    if (threadIdx.x == 0) out[g] = sm[0] + sm[1] + b_reg[0];
}

extern "C" void kernel_launch(void* const* d_in, const int* in_sizes, int n_in,
                              void* d_out, int out_size, void* d_ws, size_t ws_size,
                              hipStream_t stream) {
    const float* x      = (const float*)d_in[0];
    const int*   e_src  = (const int*)d_in[1];
    const int*   e_dst  = e_src + N_EDGES;
    const int*   batch  = (const int*)d_in[2];
    const float* W_enc  = (const float*)d_in[3];
    const float* b_enc  = (const float*)d_in[4];
    const float* gcn_W  = (const float*)d_in[5];
    const float* gcn_b  = (const float*)d_in[6];
    const float* W_reg  = (const float*)d_in[7];
    const float* b_reg  = (const float*)d_in[8];
    float* out = (float*)d_out;

    char* p = (char*)d_ws;
    auto carve = [&](size_t bytes) { char* q = p; p += (bytes + 255) & ~(size_t)255; return q; };
    float* bufA     = (float*)carve(sizeof(float) * N_NODES * HID);
    float* bufB     = (float*)carve(sizeof(float) * N_NODES * HID);
    int*   csr_src  = (int*)  carve(sizeof(int)   * (N_EDGES + N_NODES));
    float* csr_norm = (float*)carve(sizeof(float) * (N_EDGES + N_NODES));
    int*   deg      = (int*)  carve(sizeof(int)   * N_NODES);
    int*   cnt      = (int*)  carve(sizeof(int)   * N_NODES);
    int*   offsets  = (int*)  carve(sizeof(int)   * (N_NODES + 1));
    int*   incl     = (int*)  carve(sizeof(int)   * N_NODES);
    int*   bsums    = (int*)  carve(sizeof(int)   * 256);
    int*   boff     = (int*)  carve(sizeof(int)   * 256);
    float* dinv     = (float*)carve(sizeof(float) * N_NODES);
    float* pooled   = (float*)carve(sizeof(float) * N_GRAPHS * HID);

    k_init<<<NBLK, 256, 0, stream>>>(deg, cnt);
    k_deg<<<(N_EDGES + 255) / 256, 256, 0, stream>>>(e_dst, deg);
    k_dinv<<<NBLK, 256, 0, stream>>>(deg, dinv);
    k_scan1<<<NBLK, 256, 0, stream>>>(deg, incl, bsums);
    k_scan2<<<1, 256, 0, stream>>>(bsums, boff);
    k_scan3<<<NBLK, 256, 0, stream>>>(incl, boff, offsets);
    k_fill<<<(N_EDGES + N_NODES + 255) / 256, 256, 0, stream>>>(
        e_src, e_dst, dinv, offsets, cnt, csr_src, csr_norm);

    k_gemm<D_INN, true><<<512, 256, 0, stream>>>(x, W_enc, b_enc, bufA);
    for (int l = 0; l < 3; ++l) {
        k_gemm<HID, false><<<512, 256, 0, stream>>>(bufA, gcn_W + l * HID * HID, nullptr, bufB);
        k_agg<<<(N_NODES * 64 + 255) / 256, 256, 0, stream>>>(
            bufB, offsets, csr_src, csr_norm, gcn_b + l * HID, bufA);
    }
    k_pool<<<N_GRAPHS, 128, 0, stream>>>(bufA, batch, pooled);
    k_head<<<N_GRAPHS, 128, 0, stream>>>(pooled, W_reg, b_reg, out);
}

// Round 2
// 607.118 us; speedup vs baseline: 1.2782x; 1.2782x over previous
//
#include <hip/hip_runtime.h>

#define N_NODES 50000
#define N_EDGES 800000
#define D_INN 100
#define HID 128
#define N_GRAPHS 64
#define NBLK ((N_NODES + 255) / 256)   // 196
#define POOL_ROWS 128
#define POOL_BLOCKS ((N_NODES + POOL_ROWS - 1) / POOL_ROWS)  // 391

// ---------------- init: deg=1 (self loop), cnt=0 ----------------
__global__ void k_init(int* __restrict__ deg, int* __restrict__ cnt) {
    int i = blockIdx.x * 256 + threadIdx.x;
    if (i < N_NODES) { deg[i] = 1; cnt[i] = 0; }
}

// ---------------- zero the pooled-sums buffer ----------------
__global__ void k_zero(float* __restrict__ p, int n) {
    int i = blockIdx.x * 256 + threadIdx.x;
    if (i < n) p[i] = 0.f;
}

// ---------------- degree accumulation over edges ----------------
__global__ void k_deg(const int* __restrict__ dst, int* __restrict__ deg) {
    int e = blockIdx.x * 256 + threadIdx.x;
    if (e < N_EDGES) atomicAdd(&deg[dst[e]], 1);
}

__global__ void k_dinv(const int* __restrict__ deg, float* __restrict__ dinv) {
    int i = blockIdx.x * 256 + threadIdx.x;
    if (i < N_NODES) dinv[i] = rsqrtf((float)deg[i]);
}

// ---------------- two-level scan: offsets = exclusive prefix of deg ----------------
__global__ __launch_bounds__(256) void k_scan1(const int* __restrict__ deg,
                                               int* __restrict__ incl,
                                               int* __restrict__ bsums) {
    __shared__ int sm[256];
    int i = blockIdx.x * 256 + threadIdx.x;
    int v = (i < N_NODES) ? deg[i] : 0;
    sm[threadIdx.x] = v;
    __syncthreads();
    for (int off = 1; off < 256; off <<= 1) {
        int t = (threadIdx.x >= off) ? sm[threadIdx.x - off] : 0;
        __syncthreads();
        sm[threadIdx.x] += t;
        __syncthreads();
    }
    if (i < N_NODES) incl[i] = sm[threadIdx.x];
    if (threadIdx.x == 255) bsums[blockIdx.x] = sm[255];
}

__global__ __launch_bounds__(256) void k_scan2(const int* __restrict__ bsums,
                                               int* __restrict__ boff) {
    __shared__ int sm[256];
    int v = (threadIdx.x < NBLK) ? bsums[threadIdx.x] : 0;
    sm[threadIdx.x] = v;
    __syncthreads();
    for (int off = 1; off < 256; off <<= 1) {
        int t = (threadIdx.x >= off) ? sm[threadIdx.x - off] : 0;
        __syncthreads();
        sm[threadIdx.x] += t;
        __syncthreads();
    }
    boff[threadIdx.x] = sm[threadIdx.x] - v;   // exclusive
}

__global__ void k_scan3(const int* __restrict__ incl, const int* __restrict__ boff,
                        int* __restrict__ offsets) {
    int i = blockIdx.x * 256 + threadIdx.x;
    if (i < N_NODES) offsets[i + 1] = incl[i] + boff[blockIdx.x];
    if (i == 0) offsets[0] = 0;
}

// ---------------- CSR fill (edges + self loops) ----------------
__global__ void k_fill(const int* __restrict__ src, const int* __restrict__ dst,
                       const float* __restrict__ dinv, const int* __restrict__ offsets,
                       int* __restrict__ cnt, int* __restrict__ csr_src,
                       float* __restrict__ csr_norm) {
    int e = blockIdx.x * 256 + threadIdx.x;
    if (e < N_EDGES) {
        int s = src[e], d = dst[e];
        int pos = offsets[d] + atomicAdd(&cnt[d], 1);
        csr_src[pos]  = s;
        csr_norm[pos] = dinv[s] * dinv[d];
    } else if (e < N_EDGES + N_NODES) {
        int i = e - N_EDGES;
        int pos = offsets[i] + atomicAdd(&cnt[i], 1);
        csr_src[pos]  = i;
        csr_norm[pos] = dinv[i] * dinv[i];
    }
}

// ---------------- GEMM: out[N,128] = in[N,K] @ W[K,128] (+bias) ----------------
template <int K, bool BIAS>
__global__ __launch_bounds__(256) void k_gemm(const float* __restrict__ in,
                                              const float* __restrict__ W,
                                              const float* __restrict__ bias,
                                              float* __restrict__ out) {
    __shared__ float lw[K * HID];
    __shared__ float lx[32 * K];
    for (int i = threadIdx.x; i < K * HID / 4; i += 256)
        ((float4*)lw)[i] = ((const float4*)W)[i];
    const int cq = threadIdx.x & 31;   // cols 4*cq .. 4*cq+3
    const int rg = threadIdx.x >> 5;   // rows rg, rg+8, rg+16, rg+24
    float4 zero; zero.x = zero.y = zero.z = zero.w = 0.f;
    float4 bv = zero;
    if (BIAS) bv = ((const float4*)bias)[cq];
    const float4* lw4 = (const float4*)lw;
    const int nch = (N_NODES + 31) / 32;
    for (int c = blockIdx.x; c < nch; c += gridDim.x) {
        int r0 = c * 32;
        __syncthreads();
        for (int i = threadIdx.x; i < 32 * K / 4; i += 256) {
            int fi = i * 4;
            int rr = fi / K, kk = fi % K;
            int gr = r0 + rr;
            ((float4*)lx)[i] = (gr < N_NODES) ? *(const float4*)(in + gr * K + kk) : zero;
        }
        __syncthreads();
        float4 a0 = bv, a1 = bv, a2 = bv, a3 = bv;
#pragma unroll 8
        for (int k = 0; k < K; ++k) {
            float4 w = lw4[k * 32 + cq];
            float x0 = lx[(rg +  0) * K + k];
            float x1 = lx[(rg +  8) * K + k];
            float x2 = lx[(rg + 16) * K + k];
            float x3 = lx[(rg + 24) * K + k];
            a0.x = fmaf(x0, w.x, a0.x); a0.y = fmaf(x0, w.y, a0.y);
            a0.z = fmaf(x0, w.z, a0.z); a0.w = fmaf(x0, w.w, a0.w);
            a1.x = fmaf(x1, w.x, a1.x); a1.y = fmaf(x1, w.y, a1.y);
            a1.z = fmaf(x1, w.z, a1.z); a1.w = fmaf(x1, w.w, a1.w);
            a2.x = fmaf(x2, w.x, a2.x); a2.y = fmaf(x2, w.y, a2.y);
            a2.z = fmaf(x2, w.z, a2.z); a2.w = fmaf(x2, w.w, a2.w);
            a3.x = fmaf(x3, w.x, a3.x); a3.y = fmaf(x3, w.y, a3.y);
            a3.z = fmaf(x3, w.z, a3.z); a3.w = fmaf(x3, w.w, a3.w);
        }
        int gr = r0 + rg;
        if (gr      < N_NODES) *(float4*)(out + (gr     ) * HID + cq * 4) = a0;
        if (gr +  8 < N_NODES) *(float4*)(out + (gr +  8) * HID + cq * 4) = a1;
        if (gr + 16 < N_NODES) *(float4*)(out + (gr + 16) * HID + cq * 4) = a2;
        if (gr + 24 < N_NODES) *(float4*)(out + (gr + 24) * HID + cq * 4) = a3;
    }
}

// ---------------- aggregation: A[n] = relu(sum_{j in CSR(n)} norm_j * B[src_j] + b) ----
__global__ __launch_bounds__(256) void k_agg(const float* __restrict__ B,
                                             const int* __restrict__ offsets,
                                             const int* __restrict__ csr_src,
                                             const float* __restrict__ csr_norm,
                                             const float* __restrict__ bias,
                                             float* __restrict__ A) {
    int node = (blockIdx.x * 256 + threadIdx.x) >> 6;
    int lane = threadIdx.x & 63;
    if (node >= N_NODES) return;
    int beg = offsets[node], end = offsets[node + 1];
    float accx = 0.f, accy = 0.f;
    const float2* B2 = (const float2*)B;
    for (int j = beg; j < end; ++j) {
        int s = csr_src[j];
        float nv = csr_norm[j];
        float2 v = B2[s * 64 + lane];
        accx = fmaf(nv, v.x, accx);
        accy = fmaf(nv, v.y, accy);
    }
    float2 b = ((const float2*)bias)[lane];
    float2 r;
    r.x = fmaxf(accx + b.x, 0.f);
    r.y = fmaxf(accy + b.y, 0.f);
    ((float2*)A)[node * 64 + lane] = r;
}

// ---------------- pooling stage 1: per-chunk partial sums, atomic flush ----------------
// batch is sorted -> each 128-node chunk spans very few graphs.
__global__ __launch_bounds__(128) void k_pool_part(const float* __restrict__ A,
                                                   const int* __restrict__ batch,
                                                   float* __restrict__ sums) {
    int base = blockIdx.x * POOL_ROWS;
    if (base >= N_NODES) return;
    int c = threadIdx.x;
    int end = base + POOL_ROWS;
    if (end > N_NODES) end = N_NODES;
    float acc = 0.f;
    int g = batch[base];
    for (int n = base; n < end; ++n) {
        int bg = batch[n];
        if (bg != g) {
            atomicAdd(&sums[g * HID + c], acc);
            acc = 0.f;
            g = bg;
        }
        acc += A[n * HID + c];
    }
    atomicAdd(&sums[g * HID + c], acc);
}

// ---------------- head: out[g] = dot(sums[g]/cnt_g, W_reg) + b_reg ----------------
__global__ __launch_bounds__(128) void k_head(const float* __restrict__ sums,
                                              const int* __restrict__ batch,
                                              const float* __restrict__ W_reg,
                                              const float* __restrict__ b_reg,
                                              float* __restrict__ out) {
    int g = blockIdx.x;
    int lo = 0, hi = N_NODES;
    while (lo < hi) { int mid = (lo + hi) >> 1; if (batch[mid] < g) lo = mid + 1; else hi = mid; }
    int start = lo;
    hi = N_NODES;
    while (lo < hi) { int mid = (lo + hi) >> 1; if (batch[mid] < g + 1) lo = mid + 1; else hi = mid; }
    int end = lo;
    float cnt = (float)((end - start) > 0 ? (end - start) : 1);
    float v = (sums[g * HID + threadIdx.x] / cnt) * W_reg[threadIdx.x];
    for (int off = 32; off > 0; off >>= 1) v += __shfl_down(v, off);
    __shared__ float sm[2];
    if ((threadIdx.x & 63) == 0) sm[threadIdx.x >> 6] = v;
    __syncthreads();
    if (threadIdx.x == 0) out[g] = sm[0] + sm[1] + b_reg[0];
}

extern "C" void kernel_launch(void* const* d_in, const int* in_sizes, int n_in,
                              void* d_out, int out_size, void* d_ws, size_t ws_size,
                              hipStream_t stream) {
    const float* x      = (const float*)d_in[0];
    const int*   e_src  = (const int*)d_in[1];
    const int*   e_dst  = e_src + N_EDGES;
    const int*   batch  = (const int*)d_in[2];
    const float* W_enc  = (const float*)d_in[3];
    const float* b_enc  = (const float*)d_in[4];
    const float* gcn_W  = (const float*)d_in[5];
    const float* gcn_b  = (const float*)d_in[6];
    const float* W_reg  = (const float*)d_in[7];
    const float* b_reg  = (const float*)d_in[8];
    float* out = (float*)d_out;

    char* p = (char*)d_ws;
    auto carve = [&](size_t bytes) { char* q = p; p += (bytes + 255) & ~(size_t)255; return q; };
    float* bufA     = (float*)carve(sizeof(float) * N_NODES * HID);
    float* bufB     = (float*)carve(sizeof(float) * N_NODES * HID);
    int*   csr_src  = (int*)  carve(sizeof(int)   * (N_EDGES + N_NODES));
    float* csr_norm = (float*)carve(sizeof(float) * (N_EDGES + N_NODES));
    int*   deg      = (int*)  carve(sizeof(int)   * N_NODES);
    int*   cnt      = (int*)  carve(sizeof(int)   * N_NODES);
    int*   offsets  = (int*)  carve(sizeof(int)   * (N_NODES + 1));
    int*   incl     = (int*)  carve(sizeof(int)   * N_NODES);
    int*   bsums    = (int*)  carve(sizeof(int)   * 256);
    int*   boff     = (int*)  carve(sizeof(int)   * 256);
    float* dinv     = (float*)carve(sizeof(float) * N_NODES);
    float* sums     = (float*)carve(sizeof(float) * N_GRAPHS * HID);

    k_init<<<NBLK, 256, 0, stream>>>(deg, cnt);
    k_zero<<<(N_GRAPHS * HID + 255) / 256, 256, 0, stream>>>(sums, N_GRAPHS * HID);
    k_deg<<<(N_EDGES + 255) / 256, 256, 0, stream>>>(e_dst, deg);
    k_dinv<<<NBLK, 256, 0, stream>>>(deg, dinv);
    k_scan1<<<NBLK, 256, 0, stream>>>(deg, incl, bsums);
    k_scan2<<<1, 256, 0, stream>>>(bsums, boff);
    k_scan3<<<NBLK, 256, 0, stream>>>(incl, boff, offsets);
    k_fill<<<(N_EDGES + N_NODES + 255) / 256, 256, 0, stream>>>(
        e_src, e_dst, dinv, offsets, cnt, csr_src, csr_norm);

    k_gemm<D_INN, true><<<512, 256, 0, stream>>>(x, W_enc, b_enc, bufA);
    for (int l = 0; l < 3; ++l) {
        k_gemm<HID, false><<<512, 256, 0, stream>>>(bufA, gcn_W + l * HID * HID, nullptr, bufB);
        k_agg<<<(N_NODES * 64 + 255) / 256, 256, 0, stream>>>(
            bufB, offsets, csr_src, csr_norm, gcn_b + l * HID, bufA);
    }
    k_pool_part<<<POOL_BLOCKS, 128, 0, stream>>>(bufA, batch, sums);
    k_head<<<N_GRAPHS, 128, 0, stream>>>(sums, batch, W_reg, b_reg, out);
}

// Round 3
// 511.136 us; speedup vs baseline: 1.5183x; 1.1878x over previous
//
#include <hip/hip_runtime.h>

#define N_NODES 50000
#define N_EDGES 800000
#define D_INN 100
#define HID 128
#define N_GRAPHS 64
#define NBLK ((N_NODES + 255) / 256)   // 196
#define POOL_ROWS 128
#define POOL_BLOCKS ((N_NODES + POOL_ROWS - 1) / POOL_ROWS)  // 391

// ---------------- init: deg=1 (self loop), cnt=0 ----------------
__global__ void k_init(int* __restrict__ deg, int* __restrict__ cnt) {
    int i = blockIdx.x * 256 + threadIdx.x;
    if (i < N_NODES) { deg[i] = 1; cnt[i] = 0; }
}

// ---------------- zero the pooled-sums buffer ----------------
__global__ void k_zero(float* __restrict__ p, int n) {
    int i = blockIdx.x * 256 + threadIdx.x;
    if (i < n) p[i] = 0.f;
}

// ---------------- degree accumulation over edges ----------------
__global__ void k_deg(const int* __restrict__ dst, int* __restrict__ deg) {
    int e = blockIdx.x * 256 + threadIdx.x;
    if (e < N_EDGES) atomicAdd(&deg[dst[e]], 1);
}

__global__ void k_dinv(const int* __restrict__ deg, float* __restrict__ dinv) {
    int i = blockIdx.x * 256 + threadIdx.x;
    if (i < N_NODES) dinv[i] = rsqrtf((float)deg[i]);
}

// ---------------- two-level scan: offsets = exclusive prefix of deg ----------------
__global__ __launch_bounds__(256) void k_scan1(const int* __restrict__ deg,
                                               int* __restrict__ incl,
                                               int* __restrict__ bsums) {
    __shared__ int sm[256];
    int i = blockIdx.x * 256 + threadIdx.x;
    int v = (i < N_NODES) ? deg[i] : 0;
    sm[threadIdx.x] = v;
    __syncthreads();
    for (int off = 1; off < 256; off <<= 1) {
        int t = (threadIdx.x >= off) ? sm[threadIdx.x - off] : 0;
        __syncthreads();
        sm[threadIdx.x] += t;
        __syncthreads();
    }
    if (i < N_NODES) incl[i] = sm[threadIdx.x];
    if (threadIdx.x == 255) bsums[blockIdx.x] = sm[255];
}

__global__ __launch_bounds__(256) void k_scan2(const int* __restrict__ bsums,
                                               int* __restrict__ boff) {
    __shared__ int sm[256];
    int v = (threadIdx.x < NBLK) ? bsums[threadIdx.x] : 0;
    sm[threadIdx.x] = v;
    __syncthreads();
    for (int off = 1; off < 256; off <<= 1) {
        int t = (threadIdx.x >= off) ? sm[threadIdx.x - off] : 0;
        __syncthreads();
        sm[threadIdx.x] += t;
        __syncthreads();
    }
    boff[threadIdx.x] = sm[threadIdx.x] - v;   // exclusive
}

__global__ void k_scan3(const int* __restrict__ incl, const int* __restrict__ boff,
                        int* __restrict__ offsets) {
    int i = blockIdx.x * 256 + threadIdx.x;
    if (i < N_NODES) offsets[i + 1] = incl[i] + boff[blockIdx.x];
    if (i == 0) offsets[0] = 0;
}

// ---------------- CSR fill (edges + self loops) ----------------
__global__ void k_fill(const int* __restrict__ src, const int* __restrict__ dst,
                       const float* __restrict__ dinv, const int* __restrict__ offsets,
                       int* __restrict__ cnt, int* __restrict__ csr_src,
                       float* __restrict__ csr_norm) {
    int e = blockIdx.x * 256 + threadIdx.x;
    if (e < N_EDGES) {
        int s = src[e], d = dst[e];
        int pos = offsets[d] + atomicAdd(&cnt[d], 1);
        csr_src[pos]  = s;
        csr_norm[pos] = dinv[s] * dinv[d];
    } else if (e < N_EDGES + N_NODES) {
        int i = e - N_EDGES;
        int pos = offsets[i] + atomicAdd(&cnt[i], 1);
        csr_src[pos]  = i;
        csr_norm[pos] = dinv[i] * dinv[i];
    }
}

// ---------------- GEMM: out[N,128] = in[N,K] @ W[K,128] (+bias) ----------------
template <int K, bool BIAS>
__global__ __launch_bounds__(256) void k_gemm(const float* __restrict__ in,
                                              const float* __restrict__ W,
                                              const float* __restrict__ bias,
                                              float* __restrict__ out) {
    __shared__ float lw[K * HID];
    __shared__ float lx[32 * K];
    for (int i = threadIdx.x; i < K * HID / 4; i += 256)
        ((float4*)lw)[i] = ((const float4*)W)[i];
    const int cq = threadIdx.x & 31;   // cols 4*cq .. 4*cq+3
    const int rg = threadIdx.x >> 5;   // rows rg, rg+8, rg+16, rg+24
    float4 zero; zero.x = zero.y = zero.z = zero.w = 0.f;
    float4 bv = zero;
    if (BIAS) bv = ((const float4*)bias)[cq];
    const float4* lw4 = (const float4*)lw;
    const int nch = (N_NODES + 31) / 32;
    for (int c = blockIdx.x; c < nch; c += gridDim.x) {
        int r0 = c * 32;
        __syncthreads();
        for (int i = threadIdx.x; i < 32 * K / 4; i += 256) {
            int fi = i * 4;
            int rr = fi / K, kk = fi % K;
            int gr = r0 + rr;
            ((float4*)lx)[i] = (gr < N_NODES) ? *(const float4*)(in + gr * K + kk) : zero;
        }
        __syncthreads();
        float4 a0 = bv, a1 = bv, a2 = bv, a3 = bv;
#pragma unroll 8
        for (int k = 0; k < K; ++k) {
            float4 w = lw4[k * 32 + cq];
            float x0 = lx[(rg +  0) * K + k];
            float x1 = lx[(rg +  8) * K + k];
            float x2 = lx[(rg + 16) * K + k];
            float x3 = lx[(rg + 24) * K + k];
            a0.x = fmaf(x0, w.x, a0.x); a0.y = fmaf(x0, w.y, a0.y);
            a0.z = fmaf(x0, w.z, a0.z); a0.w = fmaf(x0, w.w, a0.w);
            a1.x = fmaf(x1, w.x, a1.x); a1.y = fmaf(x1, w.y, a1.y);
            a1.z = fmaf(x1, w.z, a1.z); a1.w = fmaf(x1, w.w, a1.w);
            a2.x = fmaf(x2, w.x, a2.x); a2.y = fmaf(x2, w.y, a2.y);
            a2.z = fmaf(x2, w.z, a2.z); a2.w = fmaf(x2, w.w, a2.w);
            a3.x = fmaf(x3, w.x, a3.x); a3.y = fmaf(x3, w.y, a3.y);
            a3.z = fmaf(x3, w.z, a3.z); a3.w = fmaf(x3, w.w, a3.w);
        }
        int gr = r0 + rg;
        if (gr      < N_NODES) *(float4*)(out + (gr     ) * HID + cq * 4) = a0;
        if (gr +  8 < N_NODES) *(float4*)(out + (gr +  8) * HID + cq * 4) = a1;
        if (gr + 16 < N_NODES) *(float4*)(out + (gr + 16) * HID + cq * 4) = a2;
        if (gr + 24 < N_NODES) *(float4*)(out + (gr + 24) * HID + cq * 4) = a3;
    }
}

// ---------------- aggregation: A[n] = relu(sum_{j in CSR(n)} norm_j * B[src_j] + b) ----
// one wave per node; 64 edges' (src,norm) preloaded lane-parallel, broadcast by shfl;
// gather unrolled x4 for memory-level parallelism.
__global__ __launch_bounds__(256) void k_agg(const float* __restrict__ B,
                                             const int* __restrict__ offsets,
                                             const int* __restrict__ csr_src,
                                             const float* __restrict__ csr_norm,
                                             const float* __restrict__ bias,
                                             float* __restrict__ A) {
    int node = (blockIdx.x * 256 + threadIdx.x) >> 6;
    int lane = threadIdx.x & 63;
    if (node >= N_NODES) return;
    int beg = offsets[node], end = offsets[node + 1];
    float accx = 0.f, accy = 0.f;
    const float2* B2 = (const float2*)B;
    int j = beg;
    while (j < end) {
        int take = end - j; if (take > 64) take = 64;
        int   s_l  = 0;
        float nv_l = 0.f;
        if (lane < take) {
            s_l  = csr_src[j + lane];
            nv_l = csr_norm[j + lane];
        }
        int t = 0;
        for (; t + 4 <= take; t += 4) {
            int s0 = __shfl(s_l, t + 0), s1 = __shfl(s_l, t + 1);
            int s2 = __shfl(s_l, t + 2), s3 = __shfl(s_l, t + 3);
            float n0 = __shfl(nv_l, t + 0), n1 = __shfl(nv_l, t + 1);
            float n2 = __shfl(nv_l, t + 2), n3 = __shfl(nv_l, t + 3);
            float2 v0 = B2[s0 * 64 + lane];
            float2 v1 = B2[s1 * 64 + lane];
            float2 v2 = B2[s2 * 64 + lane];
            float2 v3 = B2[s3 * 64 + lane];
            accx = fmaf(n0, v0.x, accx); accy = fmaf(n0, v0.y, accy);
            accx = fmaf(n1, v1.x, accx); accy = fmaf(n1, v1.y, accy);
            accx = fmaf(n2, v2.x, accx); accy = fmaf(n2, v2.y, accy);
            accx = fmaf(n3, v3.x, accx); accy = fmaf(n3, v3.y, accy);
        }
        for (; t < take; ++t) {
            int   s  = __shfl(s_l, t);
            float nv = __shfl(nv_l, t);
            float2 v = B2[s * 64 + lane];
            accx = fmaf(nv, v.x, accx);
            accy = fmaf(nv, v.y, accy);
        }
        j += take;
    }
    float2 b = ((const float2*)bias)[lane];
    float2 r;
    r.x = fmaxf(accx + b.x, 0.f);
    r.y = fmaxf(accy + b.y, 0.f);
    ((float2*)A)[node * 64 + lane] = r;
}

// ---------------- pooling stage 1: per-chunk partial sums, atomic flush ----------------
__global__ __launch_bounds__(128) void k_pool_part(const float* __restrict__ A,
                                                   const int* __restrict__ batch,
                                                   float* __restrict__ sums) {
    int base = blockIdx.x * POOL_ROWS;
    if (base >= N_NODES) return;
    int c = threadIdx.x;
    int end = base + POOL_ROWS;
    if (end > N_NODES) end = N_NODES;
    float acc = 0.f;
    int g = batch[base];
    for (int n = base; n < end; ++n) {
        int bg = batch[n];
        if (bg != g) {
            atomicAdd(&sums[g * HID + c], acc);
            acc = 0.f;
            g = bg;
        }
        acc += A[n * HID + c];
    }
    atomicAdd(&sums[g * HID + c], acc);
}

// ---------------- head: out[g] = dot(sums[g]/cnt_g, W_reg) + b_reg ----------------
__global__ __launch_bounds__(128) void k_head(const float* __restrict__ sums,
                                              const int* __restrict__ batch,
                                              const float* __restrict__ W_reg,
                                              const float* __restrict__ b_reg,
                                              float* __restrict__ out) {
    int g = blockIdx.x;
    int lo = 0, hi = N_NODES;
    while (lo < hi) { int mid = (lo + hi) >> 1; if (batch[mid] < g) lo = mid + 1; else hi = mid; }
    int start = lo;
    hi = N_NODES;
    while (lo < hi) { int mid = (lo + hi) >> 1; if (batch[mid] < g + 1) lo = mid + 1; else hi = mid; }
    int end = lo;
    float cnt = (float)((end - start) > 0 ? (end - start) : 1);
    float v = (sums[g * HID + threadIdx.x] / cnt) * W_reg[threadIdx.x];
    for (int off = 32; off > 0; off >>= 1) v += __shfl_down(v, off);
    __shared__ float sm[2];
    if ((threadIdx.x & 63) == 0) sm[threadIdx.x >> 6] = v;
    __syncthreads();
    if (threadIdx.x == 0) out[g] = sm[0] + sm[1] + b_reg[0];
}

extern "C" void kernel_launch(void* const* d_in, const int* in_sizes, int n_in,
                              void* d_out, int out_size, void* d_ws, size_t ws_size,
                              hipStream_t stream) {
    const float* x      = (const float*)d_in[0];
    const int*   e_src  = (const int*)d_in[1];
    const int*   e_dst  = e_src + N_EDGES;
    const int*   batch  = (const int*)d_in[2];
    const float* W_enc  = (const float*)d_in[3];
    const float* b_enc  = (const float*)d_in[4];
    const float* gcn_W  = (const float*)d_in[5];
    const float* gcn_b  = (const float*)d_in[6];
    const float* W_reg  = (const float*)d_in[7];
    const float* b_reg  = (const float*)d_in[8];
    float* out = (float*)d_out;

    char* p = (char*)d_ws;
    auto carve = [&](size_t bytes) { char* q = p; p += (bytes + 255) & ~(size_t)255; return q; };
    float* bufA     = (float*)carve(sizeof(float) * N_NODES * HID);
    float* bufB     = (float*)carve(sizeof(float) * N_NODES * HID);
    int*   csr_src  = (int*)  carve(sizeof(int)   * (N_EDGES + N_NODES));
    float* csr_norm = (float*)carve(sizeof(float) * (N_EDGES + N_NODES));
    int*   deg      = (int*)  carve(sizeof(int)   * N_NODES);
    int*   cnt      = (int*)  carve(sizeof(int)   * N_NODES);
    int*   offsets  = (int*)  carve(sizeof(int)   * (N_NODES + 1));
    int*   incl     = (int*)  carve(sizeof(int)   * N_NODES);
    int*   bsums    = (int*)  carve(sizeof(int)   * 256);
    int*   boff     = (int*)  carve(sizeof(int)   * 256);
    float* dinv     = (float*)carve(sizeof(float) * N_NODES);
    float* sums     = (float*)carve(sizeof(float) * N_GRAPHS * HID);

    k_init<<<NBLK, 256, 0, stream>>>(deg, cnt);
    k_zero<<<(N_GRAPHS * HID + 255) / 256, 256, 0, stream>>>(sums, N_GRAPHS * HID);
    k_deg<<<(N_EDGES + 255) / 256, 256, 0, stream>>>(e_dst, deg);
    k_dinv<<<NBLK, 256, 0, stream>>>(deg, dinv);
    k_scan1<<<NBLK, 256, 0, stream>>>(deg, incl, bsums);
    k_scan2<<<1, 256, 0, stream>>>(bsums, boff);
    k_scan3<<<NBLK, 256, 0, stream>>>(incl, boff, offsets);
    k_fill<<<(N_EDGES + N_NODES + 255) / 256, 256, 0, stream>>>(
        e_src, e_dst, dinv, offsets, cnt, csr_src, csr_norm);

    k_gemm<D_INN, true><<<512, 256, 0, stream>>>(x, W_enc, b_enc, bufA);
    for (int l = 0; l < 3; ++l) {
        k_gemm<HID, false><<<512, 256, 0, stream>>>(bufA, gcn_W + l * HID * HID, nullptr, bufB);
        k_agg<<<(N_NODES * 64 + 255) / 256, 256, 0, stream>>>(
            bufB, offsets, csr_src, csr_norm, gcn_b + l * HID, bufA);
    }
    k_pool_part<<<POOL_BLOCKS, 128, 0, stream>>>(bufA, batch, sums);
    k_head<<<N_GRAPHS, 128, 0, stream>>>(sums, batch, W_reg, b_reg, out);
}

// Round 4
// 435.163 us; speedup vs baseline: 1.7833x; 1.1746x over previous
//
#include <hip/hip_runtime.h>
#include <hip/hip_fp16.h>

#define N_NODES 50000
#define N_EDGES 800000
#define D_INN 100
#define HID 128
#define N_GRAPHS 64
#define NBLK ((N_NODES + 255) / 256)   // 196
#define POOL_ROWS 128
#define POOL_BLOCKS ((N_NODES + POOL_ROWS - 1) / POOL_ROWS)  // 391

// ---------------- init: deg=1 (self loop), cnt=0, zero pooled sums ----------------
__global__ void k_init(int* __restrict__ deg, int* __restrict__ cnt,
                       float* __restrict__ sums) {
    int i = blockIdx.x * 256 + threadIdx.x;
    if (i < N_NODES) { deg[i] = 1; cnt[i] = 0; }
    if (i < N_GRAPHS * HID) sums[i] = 0.f;
}

// ---------------- degree accumulation over edges ----------------
__global__ void k_deg(const int* __restrict__ dst, int* __restrict__ deg) {
    int e = blockIdx.x * 256 + threadIdx.x;
    if (e < N_EDGES) atomicAdd(&deg[dst[e]], 1);
}

__global__ void k_dinv(const int* __restrict__ deg, float* __restrict__ dinv) {
    int i = blockIdx.x * 256 + threadIdx.x;
    if (i < N_NODES) dinv[i] = rsqrtf((float)deg[i]);
}

// ---------------- two-level scan: offsets = exclusive prefix of deg ----------------
__global__ __launch_bounds__(256) void k_scan1(const int* __restrict__ deg,
                                               int* __restrict__ incl,
                                               int* __restrict__ bsums) {
    __shared__ int sm[256];
    int i = blockIdx.x * 256 + threadIdx.x;
    int v = (i < N_NODES) ? deg[i] : 0;
    sm[threadIdx.x] = v;
    __syncthreads();
    for (int off = 1; off < 256; off <<= 1) {
        int t = (threadIdx.x >= off) ? sm[threadIdx.x - off] : 0;
        __syncthreads();
        sm[threadIdx.x] += t;
        __syncthreads();
    }
    if (i < N_NODES) incl[i] = sm[threadIdx.x];
    if (threadIdx.x == 255) bsums[blockIdx.x] = sm[255];
}

__global__ __launch_bounds__(256) void k_scan2(const int* __restrict__ bsums,
                                               int* __restrict__ boff) {
    __shared__ int sm[256];
    int v = (threadIdx.x < NBLK) ? bsums[threadIdx.x] : 0;
    sm[threadIdx.x] = v;
    __syncthreads();
    for (int off = 1; off < 256; off <<= 1) {
        int t = (threadIdx.x >= off) ? sm[threadIdx.x - off] : 0;
        __syncthreads();
        sm[threadIdx.x] += t;
        __syncthreads();
    }
    boff[threadIdx.x] = sm[threadIdx.x] - v;   // exclusive
}

__global__ void k_scan3(const int* __restrict__ incl, const int* __restrict__ boff,
                        int* __restrict__ offsets) {
    int i = blockIdx.x * 256 + threadIdx.x;
    if (i < N_NODES) offsets[i + 1] = incl[i] + boff[blockIdx.x];
    if (i == 0) offsets[0] = 0;
}

// ---------------- CSR fill (edges + self loops); norms folded elsewhere -----------
__global__ void k_fill(const int* __restrict__ src, const int* __restrict__ dst,
                       const int* __restrict__ offsets, int* __restrict__ cnt,
                       int* __restrict__ csr_src) {
    int e = blockIdx.x * 256 + threadIdx.x;
    if (e < N_EDGES) {
        int s = src[e], d = dst[e];
        int pos = offsets[d] + atomicAdd(&cnt[d], 1);
        csr_src[pos] = s;
    } else if (e < N_EDGES + N_NODES) {
        int i = e - N_EDGES;
        int pos = offsets[i] + atomicAdd(&cnt[i], 1);
        csr_src[pos] = i;
    }
}

// ---------------- GEMM: out[N,128] = in[N,K] @ W[K,128] (+bias) ----------------
// FOLD: out_fp16[r][c] = fp16( acc * dinv[r] )  (message buffer for aggregation)
template <int K, bool BIAS, bool FOLD>
__global__ __launch_bounds__(256) void k_gemm(const float* __restrict__ in,
                                              const float* __restrict__ W,
                                              const float* __restrict__ bias,
                                              const float* __restrict__ dinv,
                                              void* __restrict__ outp) {
    __shared__ float lw[K * HID];
    __shared__ float lx[32 * K];
    for (int i = threadIdx.x; i < K * HID / 4; i += 256)
        ((float4*)lw)[i] = ((const float4*)W)[i];
    const int cq = threadIdx.x & 31;   // cols 4*cq .. 4*cq+3
    const int rg = threadIdx.x >> 5;   // rows rg, rg+8, rg+16, rg+24
    float4 zero; zero.x = zero.y = zero.z = zero.w = 0.f;
    float4 bv = zero;
    if (BIAS) bv = ((const float4*)bias)[cq];
    const float4* lw4 = (const float4*)lw;
    float* outf = (float*)outp;
    __half* outh = (__half*)outp;
    const int nch = (N_NODES + 31) / 32;
    for (int c = blockIdx.x; c < nch; c += gridDim.x) {
        int r0 = c * 32;
        __syncthreads();
        for (int i = threadIdx.x; i < 32 * K / 4; i += 256) {
            int fi = i * 4;
            int rr = fi / K, kk = fi % K;
            int gr = r0 + rr;
            ((float4*)lx)[i] = (gr < N_NODES) ? *(const float4*)(in + gr * K + kk) : zero;
        }
        __syncthreads();
        float4 a0 = bv, a1 = bv, a2 = bv, a3 = bv;
#pragma unroll 8
        for (int k = 0; k < K; ++k) {
            float4 w = lw4[k * 32 + cq];
            float x0 = lx[(rg +  0) * K + k];
            float x1 = lx[(rg +  8) * K + k];
            float x2 = lx[(rg + 16) * K + k];
            float x3 = lx[(rg + 24) * K + k];
            a0.x = fmaf(x0, w.x, a0.x); a0.y = fmaf(x0, w.y, a0.y);
            a0.z = fmaf(x0, w.z, a0.z); a0.w = fmaf(x0, w.w, a0.w);
            a1.x = fmaf(x1, w.x, a1.x); a1.y = fmaf(x1, w.y, a1.y);
            a1.z = fmaf(x1, w.z, a1.z); a1.w = fmaf(x1, w.w, a1.w);
            a2.x = fmaf(x2, w.x, a2.x); a2.y = fmaf(x2, w.y, a2.y);
            a2.z = fmaf(x2, w.z, a2.z); a2.w = fmaf(x2, w.w, a2.w);
            a3.x = fmaf(x3, w.x, a3.x); a3.y = fmaf(x3, w.y, a3.y);
            a3.z = fmaf(x3, w.z, a3.z); a3.w = fmaf(x3, w.w, a3.w);
        }
        int gr = r0 + rg;
        if (FOLD) {
#pragma unroll
            for (int q = 0; q < 4; ++q) {
                int r = gr + q * 8;
                if (r < N_NODES) {
                    float4 a = (q == 0) ? a0 : (q == 1) ? a1 : (q == 2) ? a2 : a3;
                    float s = dinv[r];
                    ushort4 h;
                    h.x = __half_as_ushort(__float2half(a.x * s));
                    h.y = __half_as_ushort(__float2half(a.y * s));
                    h.z = __half_as_ushort(__float2half(a.z * s));
                    h.w = __half_as_ushort(__float2half(a.w * s));
                    *(ushort4*)(outh + r * HID + cq * 4) = h;
                }
            }
        } else {
            if (gr      < N_NODES) *(float4*)(outf + (gr     ) * HID + cq * 4) = a0;
            if (gr +  8 < N_NODES) *(float4*)(outf + (gr +  8) * HID + cq * 4) = a1;
            if (gr + 16 < N_NODES) *(float4*)(outf + (gr + 16) * HID + cq * 4) = a2;
            if (gr + 24 < N_NODES) *(float4*)(outf + (gr + 24) * HID + cq * 4) = a3;
        }
    }
}

// ---------------- aggregation: A[n] = relu(dinv[n] * sum_j B[src_j] + b) -------------
// B is fp16 with dinv[src] pre-folded. One wave per node, half2 per lane.
__global__ __launch_bounds__(256) void k_agg(const __half* __restrict__ B,
                                             const int* __restrict__ offsets,
                                             const int* __restrict__ csr_src,
                                             const float* __restrict__ dinv,
                                             const float* __restrict__ bias,
                                             float* __restrict__ A) {
    int node = (blockIdx.x * 256 + threadIdx.x) >> 6;
    int lane = threadIdx.x & 63;
    if (node >= N_NODES) return;
    int beg = offsets[node], end = offsets[node + 1];
    float ax0 = 0.f, ay0 = 0.f, ax1 = 0.f, ay1 = 0.f;
    const __half2* B2 = (const __half2*)B;
    int j = beg;
    while (j < end) {
        int take = end - j; if (take > 64) take = 64;
        int s_l = (lane < take) ? csr_src[j + lane] : 0;
        int t = 0;
        for (; t + 4 <= take; t += 4) {
            int s0 = __shfl(s_l, t + 0), s1 = __shfl(s_l, t + 1);
            int s2 = __shfl(s_l, t + 2), s3 = __shfl(s_l, t + 3);
            __half2 v0 = B2[s0 * 64 + lane];
            __half2 v1 = B2[s1 * 64 + lane];
            __half2 v2 = B2[s2 * 64 + lane];
            __half2 v3 = B2[s3 * 64 + lane];
            float2 f0 = __half22float2(v0);
            float2 f1 = __half22float2(v1);
            float2 f2 = __half22float2(v2);
            float2 f3 = __half22float2(v3);
            ax0 += f0.x; ay0 += f0.y;
            ax1 += f1.x; ay1 += f1.y;
            ax0 += f2.x; ay0 += f2.y;
            ax1 += f3.x; ay1 += f3.y;
        }
        for (; t < take; ++t) {
            int s = __shfl(s_l, t);
            float2 f = __half22float2(B2[s * 64 + lane]);
            ax0 += f.x; ay0 += f.y;
        }
        j += take;
    }
    float dn = dinv[node];
    float2 b = ((const float2*)bias)[lane];
    float2 r;
    r.x = fmaxf(fmaf(dn, ax0 + ax1, b.x), 0.f);
    r.y = fmaxf(fmaf(dn, ay0 + ay1, b.y), 0.f);
    ((float2*)A)[node * 64 + lane] = r;
}

// ---------------- pooling stage 1: per-chunk partial sums, atomic flush ----------------
__global__ __launch_bounds__(128) void k_pool_part(const float* __restrict__ A,
                                                   const int* __restrict__ batch,
                                                   float* __restrict__ sums) {
    int base = blockIdx.x * POOL_ROWS;
    if (base >= N_NODES) return;
    int c = threadIdx.x;
    int end = base + POOL_ROWS;
    if (end > N_NODES) end = N_NODES;
    float acc = 0.f;
    int g = batch[base];
    for (int n = base; n < end; ++n) {
        int bg = batch[n];
        if (bg != g) {
            atomicAdd(&sums[g * HID + c], acc);
            acc = 0.f;
            g = bg;
        }
        acc += A[n * HID + c];
    }
    atomicAdd(&sums[g * HID + c], acc);
}

// ---------------- head: out[g] = dot(sums[g]/cnt_g, W_reg) + b_reg ----------------
__global__ __launch_bounds__(128) void k_head(const float* __restrict__ sums,
                                              const int* __restrict__ batch,
                                              const float* __restrict__ W_reg,
                                              const float* __restrict__ b_reg,
                                              float* __restrict__ out) {
    int g = blockIdx.x;
    int lo = 0, hi = N_NODES;
    while (lo < hi) { int mid = (lo + hi) >> 1; if (batch[mid] < g) lo = mid + 1; else hi = mid; }
    int start = lo;
    hi = N_NODES;
    while (lo < hi) { int mid = (lo + hi) >> 1; if (batch[mid] < g + 1) lo = mid + 1; else hi = mid; }
    int end = lo;
    float cnt = (float)((end - start) > 0 ? (end - start) : 1);
    float v = (sums[g * HID + threadIdx.x] / cnt) * W_reg[threadIdx.x];
    for (int off = 32; off > 0; off >>= 1) v += __shfl_down(v, off);
    __shared__ float sm[2];
    if ((threadIdx.x & 63) == 0) sm[threadIdx.x >> 6] = v;
    __syncthreads();
    if (threadIdx.x == 0) out[g] = sm[0] + sm[1] + b_reg[0];
}

extern "C" void kernel_launch(void* const* d_in, const int* in_sizes, int n_in,
                              void* d_out, int out_size, void* d_ws, size_t ws_size,
                              hipStream_t stream) {
    const float* x      = (const float*)d_in[0];
    const int*   e_src  = (const int*)d_in[1];
    const int*   e_dst  = e_src + N_EDGES;
    const int*   batch  = (const int*)d_in[2];
    const float* W_enc  = (const float*)d_in[3];
    const float* b_enc  = (const float*)d_in[4];
    const float* gcn_W  = (const float*)d_in[5];
    const float* gcn_b  = (const float*)d_in[6];
    const float* W_reg  = (const float*)d_in[7];
    const float* b_reg  = (const float*)d_in[8];
    float* out = (float*)d_out;

    char* p = (char*)d_ws;
    auto carve = [&](size_t bytes) { char* q = p; p += (bytes + 255) & ~(size_t)255; return q; };
    float*  bufA    = (float*) carve(sizeof(float)  * N_NODES * HID);
    __half* bufB    = (__half*)carve(sizeof(__half) * N_NODES * HID);
    int*    csr_src = (int*)   carve(sizeof(int)    * (N_EDGES + N_NODES));
    int*    deg     = (int*)   carve(sizeof(int)    * N_NODES);
    int*    cnt     = (int*)   carve(sizeof(int)    * N_NODES);
    int*    offsets = (int*)   carve(sizeof(int)    * (N_NODES + 1));
    int*    incl    = (int*)   carve(sizeof(int)    * N_NODES);
    int*    bsums   = (int*)   carve(sizeof(int)    * 256);
    int*    boff    = (int*)   carve(sizeof(int)    * 256);
    float*  dinv    = (float*) carve(sizeof(float)  * N_NODES);
    float*  sums    = (float*) carve(sizeof(float)  * N_GRAPHS * HID);

    k_init<<<NBLK, 256, 0, stream>>>(deg, cnt, sums);
    k_deg<<<(N_EDGES + 255) / 256, 256, 0, stream>>>(e_dst, deg);
    k_dinv<<<NBLK, 256, 0, stream>>>(deg, dinv);
    k_scan1<<<NBLK, 256, 0, stream>>>(deg, incl, bsums);
    k_scan2<<<1, 256, 0, stream>>>(bsums, boff);
    k_scan3<<<NBLK, 256, 0, stream>>>(incl, boff, offsets);
    k_fill<<<(N_EDGES + N_NODES + 255) / 256, 256, 0, stream>>>(
        e_src, e_dst, offsets, cnt, csr_src);

    k_gemm<D_INN, true, false><<<512, 256, 0, stream>>>(x, W_enc, b_enc, nullptr, bufA);
    for (int l = 0; l < 3; ++l) {
        k_gemm<HID, false, true><<<512, 256, 0, stream>>>(
            bufA, gcn_W + l * HID * HID, nullptr, dinv, bufB);
        k_agg<<<(N_NODES * 64 + 255) / 256, 256, 0, stream>>>(
            bufB, offsets, csr_src, dinv, gcn_b + l * HID, bufA);
    }
    k_pool_part<<<POOL_BLOCKS, 128, 0, stream>>>(bufA, batch, sums);
    k_head<<<N_GRAPHS, 128, 0, stream>>>(sums, batch, W_reg, b_reg, out);
}

// Round 5
// 401.557 us; speedup vs baseline: 1.9326x; 1.0837x over previous
//
#include <hip/hip_runtime.h>
#include <hip/hip_fp16.h>

#define N_NODES 50000
#define N_EDGES 800000
#define D_INN 100
#define HID 128
#define N_GRAPHS 64
#define NBLK ((N_NODES + 255) / 256)   // 196
#define POOL_ROWS 128
#define POOL_BLOCKS ((N_NODES + POOL_ROWS - 1) / POOL_ROWS)  // 391

typedef _Float16 f16x8 __attribute__((ext_vector_type(8)));
typedef float f32x4 __attribute__((ext_vector_type(4)));

// ---------------- init: deg=1 (self loop), zero pooled sums ----------------
__global__ void k_init(int* __restrict__ deg, float* __restrict__ sums) {
    int i = blockIdx.x * 256 + threadIdx.x;
    if (i < N_NODES) deg[i] = 1;
    if (i < N_GRAPHS * HID) sums[i] = 0.f;
}

// ---------------- degree accumulation over edges (4 edges/thread) ----------------
__global__ void k_deg(const int* __restrict__ dst, int* __restrict__ deg) {
    int t = blockIdx.x * 256 + threadIdx.x;
    if (t < N_EDGES / 4) {
        int4 d = ((const int4*)dst)[t];
        atomicAdd(&deg[d.x], 1);
        atomicAdd(&deg[d.y], 1);
        atomicAdd(&deg[d.z], 1);
        atomicAdd(&deg[d.w], 1);
    }
}

__global__ void k_dinv(const int* __restrict__ deg, float* __restrict__ dinv) {
    int i = blockIdx.x * 256 + threadIdx.x;
    if (i < N_NODES) dinv[i] = rsqrtf((float)deg[i]);
}

// ---------------- two-level scan: offsets = exclusive prefix of deg ----------------
__global__ __launch_bounds__(256) void k_scan1(const int* __restrict__ deg,
                                               int* __restrict__ incl,
                                               int* __restrict__ bsums) {
    __shared__ int sm[256];
    int i = blockIdx.x * 256 + threadIdx.x;
    int v = (i < N_NODES) ? deg[i] : 0;
    sm[threadIdx.x] = v;
    __syncthreads();
    for (int off = 1; off < 256; off <<= 1) {
        int t = (threadIdx.x >= off) ? sm[threadIdx.x - off] : 0;
        __syncthreads();
        sm[threadIdx.x] += t;
        __syncthreads();
    }
    if (i < N_NODES) incl[i] = sm[threadIdx.x];
    if (threadIdx.x == 255) bsums[blockIdx.x] = sm[255];
}

__global__ __launch_bounds__(256) void k_scan2(const int* __restrict__ bsums,
                                               int* __restrict__ boff) {
    __shared__ int sm[256];
    int v = (threadIdx.x < NBLK) ? bsums[threadIdx.x] : 0;
    sm[threadIdx.x] = v;
    __syncthreads();
    for (int off = 1; off < 256; off <<= 1) {
        int t = (threadIdx.x >= off) ? sm[threadIdx.x - off] : 0;
        __syncthreads();
        sm[threadIdx.x] += t;
        __syncthreads();
    }
    boff[threadIdx.x] = sm[threadIdx.x] - v;   // exclusive
}

// offsets[i+1]; self-loop placed at slot offsets[i] (no atomic); cursor = offsets[i]+1
__global__ void k_scan3(const int* __restrict__ incl, const int* __restrict__ boff,
                        const int* __restrict__ deg, int* __restrict__ offsets,
                        int* __restrict__ cursor, int* __restrict__ csr_src) {
    int i = blockIdx.x * 256 + threadIdx.x;
    if (i < N_NODES) {
        int off1 = incl[i] + boff[blockIdx.x];
        offsets[i + 1] = off1;
        int p0 = off1 - deg[i];
        csr_src[p0] = i;        // self loop first in segment
        cursor[i] = p0 + 1;
    }
    if (i == 0) offsets[0] = 0;
}

// ---------------- CSR fill: one atomic per edge (2 edges/thread) ----------------
__global__ void k_fill(const int* __restrict__ src, const int* __restrict__ dst,
                       int* __restrict__ cursor, int* __restrict__ csr_src) {
    int t = blockIdx.x * 256 + threadIdx.x;
    if (t < N_EDGES / 2) {
        int2 s = ((const int2*)src)[t];
        int2 d = ((const int2*)dst)[t];
        int p0 = atomicAdd(&cursor[d.x], 1);
        csr_src[p0] = s.x;
        int p1 = atomicAdd(&cursor[d.y], 1);
        csr_src[p1] = s.y;
    }
}

// ---------------- W transpose + fp16: Wt[l][c][k] = fp16(W[l][k][c]) ----------------
__global__ void k_wt(const float* __restrict__ W, __half* __restrict__ Wt) {
    int i = blockIdx.x * 256 + threadIdx.x;
    if (i < 3 * HID * HID) {
        int l = i >> 14, rem = i & 16383;
        int c = rem >> 7, k = rem & 127;
        Wt[(l << 14) + c * HID + k] = __float2half(W[(l << 14) + k * HID + c]);
    }
}

// ---------------- encoder GEMM: hA[N,128] = fp16(x[N,100] @ W_enc + b_enc) ----------
__global__ __launch_bounds__(256) void k_gemm_enc(const float* __restrict__ in,
                                                  const float* __restrict__ W,
                                                  const float* __restrict__ bias,
                                                  __half* __restrict__ outh) {
    const int K = D_INN;
    __shared__ float lw[K * HID];
    __shared__ float lx[32 * K];
    for (int i = threadIdx.x; i < K * HID / 4; i += 256)
        ((float4*)lw)[i] = ((const float4*)W)[i];
    const int cq = threadIdx.x & 31;
    const int rg = threadIdx.x >> 5;
    float4 zero; zero.x = zero.y = zero.z = zero.w = 0.f;
    float4 bv = ((const float4*)bias)[cq];
    const float4* lw4 = (const float4*)lw;
    const int nch = (N_NODES + 31) / 32;
    for (int c = blockIdx.x; c < nch; c += gridDim.x) {
        int r0 = c * 32;
        __syncthreads();
        for (int i = threadIdx.x; i < 32 * K / 4; i += 256) {
            int fi = i * 4;
            int rr = fi / K, kk = fi % K;
            int gr = r0 + rr;
            ((float4*)lx)[i] = (gr < N_NODES) ? *(const float4*)(in + gr * K + kk) : zero;
        }
        __syncthreads();
        float4 a0 = bv, a1 = bv, a2 = bv, a3 = bv;
#pragma unroll 4
        for (int k = 0; k < K; ++k) {
            float4 w = lw4[k * 32 + cq];
            float x0 = lx[(rg +  0) * K + k];
            float x1 = lx[(rg +  8) * K + k];
            float x2 = lx[(rg + 16) * K + k];
            float x3 = lx[(rg + 24) * K + k];
            a0.x = fmaf(x0, w.x, a0.x); a0.y = fmaf(x0, w.y, a0.y);
            a0.z = fmaf(x0, w.z, a0.z); a0.w = fmaf(x0, w.w, a0.w);
            a1.x = fmaf(x1, w.x, a1.x); a1.y = fmaf(x1, w.y, a1.y);
            a1.z = fmaf(x1, w.z, a1.z); a1.w = fmaf(x1, w.w, a1.w);
            a2.x = fmaf(x2, w.x, a2.x); a2.y = fmaf(x2, w.y, a2.y);
            a2.z = fmaf(x2, w.z, a2.z); a2.w = fmaf(x2, w.w, a2.w);
            a3.x = fmaf(x3, w.x, a3.x); a3.y = fmaf(x3, w.y, a3.y);
            a3.z = fmaf(x3, w.z, a3.z); a3.w = fmaf(x3, w.w, a3.w);
        }
        int gr = r0 + rg;
#pragma unroll
        for (int q = 0; q < 4; ++q) {
            int r = gr + q * 8;
            if (r < N_NODES) {
                float4 a = (q == 0) ? a0 : (q == 1) ? a1 : (q == 2) ? a2 : a3;
                ushort4 h;
                h.x = __half_as_ushort(__float2half(a.x));
                h.y = __half_as_ushort(__float2half(a.y));
                h.z = __half_as_ushort(__float2half(a.z));
                h.w = __half_as_ushort(__float2half(a.w));
                *(ushort4*)(outh + r * HID + cq * 4) = h;
            }
        }
    }
}

// ---------------- layer GEMM via MFMA: msg = fp16( dinv * (hA @ W) ) ----------------
// wave w owns cols [w*32, w*32+32); B-slice (32 cols x 128 K) cached in 8 register frags.
// Per 16-row chunk: 4 A-frag loads + 8 MFMAs. fp32 accumulate.
__global__ __launch_bounds__(256) void k_gemm_mfma(const _Float16* __restrict__ A,
                                                   const _Float16* __restrict__ Wt,
                                                   const float* __restrict__ dinv,
                                                   _Float16* __restrict__ out) {
    const int lane = threadIdx.x & 63;
    const int wave = threadIdx.x >> 6;   // 0..3
    const int l15  = lane & 15;
    const int lhi  = lane >> 4;          // 0..3
    f16x8 bf0[4], bf1[4];
#pragma unroll
    for (int ks = 0; ks < 4; ++ks) {
        int col0 = wave * 32 + l15;
        int col1 = wave * 32 + 16 + l15;
        bf0[ks] = *(const f16x8*)(Wt + col0 * HID + ks * 32 + lhi * 8);
        bf1[ks] = *(const f16x8*)(Wt + col1 * HID + ks * 32 + lhi * 8);
    }
    for (int chunk = blockIdx.x; chunk < N_NODES / 16; chunk += gridDim.x) {
        int row0 = chunk * 16;
        const _Float16* Ar = A + (row0 + l15) * HID + lhi * 8;
        f16x8 af0 = *(const f16x8*)(Ar);
        f16x8 af1 = *(const f16x8*)(Ar + 32);
        f16x8 af2 = *(const f16x8*)(Ar + 64);
        f16x8 af3 = *(const f16x8*)(Ar + 96);
        f32x4 acc0 = {0.f, 0.f, 0.f, 0.f};
        f32x4 acc1 = {0.f, 0.f, 0.f, 0.f};
        acc0 = __builtin_amdgcn_mfma_f32_16x16x32_f16(af0, bf0[0], acc0, 0, 0, 0);
        acc1 = __builtin_amdgcn_mfma_f32_16x16x32_f16(af0, bf1[0], acc1, 0, 0, 0);
        acc0 = __builtin_amdgcn_mfma_f32_16x16x32_f16(af1, bf0[1], acc0, 0, 0, 0);
        acc1 = __builtin_amdgcn_mfma_f32_16x16x32_f16(af1, bf1[1], acc1, 0, 0, 0);
        acc0 = __builtin_amdgcn_mfma_f32_16x16x32_f16(af2, bf0[2], acc0, 0, 0, 0);
        acc1 = __builtin_amdgcn_mfma_f32_16x16x32_f16(af2, bf1[2], acc1, 0, 0, 0);
        acc0 = __builtin_amdgcn_mfma_f32_16x16x32_f16(af3, bf0[3], acc0, 0, 0, 0);
        acc1 = __builtin_amdgcn_mfma_f32_16x16x32_f16(af3, bf1[3], acc1, 0, 0, 0);
#pragma unroll
        for (int r = 0; r < 4; ++r) {
            int row = row0 + lhi * 4 + r;
            float dr = dinv[row];
            out[row * HID + wave * 32 + l15]      = (_Float16)(acc0[r] * dr);
            out[row * HID + wave * 32 + 16 + l15] = (_Float16)(acc1[r] * dr);
        }
    }
}

// ---------------- aggregation: hA[n] = fp16(relu(dinv[n] * sum_j msg[src_j] + b)) ----
__global__ __launch_bounds__(256) void k_agg(const __half* __restrict__ B,
                                             const int* __restrict__ offsets,
                                             const int* __restrict__ csr_src,
                                             const float* __restrict__ dinv,
                                             const float* __restrict__ bias,
                                             __half* __restrict__ A) {
    int node = (blockIdx.x * 256 + threadIdx.x) >> 6;
    int lane = threadIdx.x & 63;
    if (node >= N_NODES) return;
    int beg = offsets[node], end = offsets[node + 1];
    float ax0 = 0.f, ay0 = 0.f, ax1 = 0.f, ay1 = 0.f;
    const __half2* B2 = (const __half2*)B;
    int j = beg;
    while (j < end) {
        int take = end - j; if (take > 64) take = 64;
        int s_l = (lane < take) ? csr_src[j + lane] : 0;
        int t = 0;
        for (; t + 4 <= take; t += 4) {
            int s0 = __shfl(s_l, t + 0), s1 = __shfl(s_l, t + 1);
            int s2 = __shfl(s_l, t + 2), s3 = __shfl(s_l, t + 3);
            float2 f0 = __half22float2(B2[s0 * 64 + lane]);
            float2 f1 = __half22float2(B2[s1 * 64 + lane]);
            float2 f2 = __half22float2(B2[s2 * 64 + lane]);
            float2 f3 = __half22float2(B2[s3 * 64 + lane]);
            ax0 += f0.x; ay0 += f0.y;
            ax1 += f1.x; ay1 += f1.y;
            ax0 += f2.x; ay0 += f2.y;
            ax1 += f3.x; ay1 += f3.y;
        }
        for (; t < take; ++t) {
            int s = __shfl(s_l, t);
            float2 f = __half22float2(B2[s * 64 + lane]);
            ax0 += f.x; ay0 += f.y;
        }
        j += take;
    }
    float dn = dinv[node];
    float2 b = ((const float2*)bias)[lane];
    float rx = fmaxf(fmaf(dn, ax0 + ax1, b.x), 0.f);
    float ry = fmaxf(fmaf(dn, ay0 + ay1, b.y), 0.f);
    ((__half2*)A)[node * 64 + lane] = __floats2half2_rn(rx, ry);
}

// ---------------- pooling stage 1: per-chunk partial sums, atomic flush ----------------
__global__ __launch_bounds__(64) void k_pool_part(const __half* __restrict__ A,
                                                  const int* __restrict__ batch,
                                                  float* __restrict__ sums) {
    int base = blockIdx.x * POOL_ROWS;
    if (base >= N_NODES) return;
    int c = threadIdx.x;           // half2 column index 0..63
    int end = base + POOL_ROWS;
    if (end > N_NODES) end = N_NODES;
    const __half2* A2 = (const __half2*)A;
    float ax = 0.f, ay = 0.f;
    int g = batch[base];
    for (int n = base; n < end; ++n) {
        int bg = batch[n];
        if (bg != g) {
            atomicAdd(&sums[g * HID + 2 * c], ax);
            atomicAdd(&sums[g * HID + 2 * c + 1], ay);
            ax = 0.f; ay = 0.f;
            g = bg;
        }
        float2 f = __half22float2(A2[n * 64 + c]);
        ax += f.x; ay += f.y;
    }
    atomicAdd(&sums[g * HID + 2 * c], ax);
    atomicAdd(&sums[g * HID + 2 * c + 1], ay);
}

// ---------------- head: out[g] = dot(sums[g]/cnt_g, W_reg) + b_reg ----------------
__global__ __launch_bounds__(128) void k_head(const float* __restrict__ sums,
                                              const int* __restrict__ batch,
                                              const float* __restrict__ W_reg,
                                              const float* __restrict__ b_reg,
                                              float* __restrict__ out) {
    int g = blockIdx.x;
    int lo = 0, hi = N_NODES;
    while (lo < hi) { int mid = (lo + hi) >> 1; if (batch[mid] < g) lo = mid + 1; else hi = mid; }
    int start = lo;
    hi = N_NODES;
    while (lo < hi) { int mid = (lo + hi) >> 1; if (batch[mid] < g + 1) lo = mid + 1; else hi = mid; }
    int end = lo;
    float cnt = (float)((end - start) > 0 ? (end - start) : 1);
    float v = (sums[g * HID + threadIdx.x] / cnt) * W_reg[threadIdx.x];
    for (int off = 32; off > 0; off >>= 1) v += __shfl_down(v, off);
    __shared__ float sm[2];
    if ((threadIdx.x & 63) == 0) sm[threadIdx.x >> 6] = v;
    __syncthreads();
    if (threadIdx.x == 0) out[g] = sm[0] + sm[1] + b_reg[0];
}

extern "C" void kernel_launch(void* const* d_in, const int* in_sizes, int n_in,
                              void* d_out, int out_size, void* d_ws, size_t ws_size,
                              hipStream_t stream) {
    const float* x      = (const float*)d_in[0];
    const int*   e_src  = (const int*)d_in[1];
    const int*   e_dst  = e_src + N_EDGES;
    const int*   batch  = (const int*)d_in[2];
    const float* W_enc  = (const float*)d_in[3];
    const float* b_enc  = (const float*)d_in[4];
    const float* gcn_W  = (const float*)d_in[5];
    const float* gcn_b  = (const float*)d_in[6];
    const float* W_reg  = (const float*)d_in[7];
    const float* b_reg  = (const float*)d_in[8];
    float* out = (float*)d_out;

    char* p = (char*)d_ws;
    auto carve = [&](size_t bytes) { char* q = p; p += (bytes + 255) & ~(size_t)255; return q; };
    __half* hA      = (__half*)carve(sizeof(__half) * N_NODES * HID);
    __half* msg     = (__half*)carve(sizeof(__half) * N_NODES * HID);
    __half* Wt      = (__half*)carve(sizeof(__half) * 3 * HID * HID);
    int*    csr_src = (int*)   carve(sizeof(int)    * (N_EDGES + N_NODES));
    int*    deg     = (int*)   carve(sizeof(int)    * N_NODES);
    int*    cursor  = (int*)   carve(sizeof(int)    * N_NODES);
    int*    offsets = (int*)   carve(sizeof(int)    * (N_NODES + 1));
    int*    incl    = (int*)   carve(sizeof(int)    * N_NODES);
    int*    bsums   = (int*)   carve(sizeof(int)    * 256);
    int*    boff    = (int*)   carve(sizeof(int)    * 256);
    float*  dinv    = (float*) carve(sizeof(float)  * N_NODES);
    float*  sums    = (float*) carve(sizeof(float)  * N_GRAPHS * HID);

    k_init<<<NBLK, 256, 0, stream>>>(deg, sums);
    k_deg<<<(N_EDGES / 4 + 255) / 256, 256, 0, stream>>>(e_dst, deg);
    k_dinv<<<NBLK, 256, 0, stream>>>(deg, dinv);
    k_scan1<<<NBLK, 256, 0, stream>>>(deg, incl, bsums);
    k_scan2<<<1, 256, 0, stream>>>(bsums, boff);
    k_scan3<<<NBLK, 256, 0, stream>>>(incl, boff, deg, offsets, cursor, csr_src);
    k_fill<<<(N_EDGES / 2 + 255) / 256, 256, 0, stream>>>(e_src, e_dst, cursor, csr_src);
    k_wt<<<(3 * HID * HID + 255) / 256, 256, 0, stream>>>(gcn_W, Wt);

    k_gemm_enc<<<512, 256, 0, stream>>>(x, W_enc, b_enc, hA);
    for (int l = 0; l < 3; ++l) {
        k_gemm_mfma<<<640, 256, 0, stream>>>(
            (const _Float16*)hA, (const _Float16*)(Wt + l * HID * HID), dinv,
            (_Float16*)msg);
        k_agg<<<(N_NODES * 64 + 255) / 256, 256, 0, stream>>>(
            msg, offsets, csr_src, dinv, gcn_b + l * HID, hA);
    }
    k_pool_part<<<POOL_BLOCKS, 64, 0, stream>>>(hA, batch, sums);
    k_head<<<N_GRAPHS, 128, 0, stream>>>(sums, batch, W_reg, b_reg, out);
}